// Round 1
// baseline (604.028 us; speedup 1.0000x reference)
//
#include <hip/hip_runtime.h>

#define T_TOKENS 4096
#define DIM      1024
#define HID      4096
#define NE       8
#define TOPK     2

typedef __attribute__((ext_vector_type(8))) short short8;
typedef __attribute__((ext_vector_type(4))) float f32x4;

__device__ __forceinline__ unsigned short f2bf(float f) {
    unsigned int u = __builtin_bit_cast(unsigned int, f);
    u += 0x7fffu + ((u >> 16) & 1u);
    return (unsigned short)(u >> 16);
}

// ---------------- router: logits -> top2 -> softmax -> scatter ----------------
__global__ void router_kernel(const float* __restrict__ x, const float* __restrict__ Wg,
                              const float* __restrict__ bg, int* __restrict__ counts,
                              int* __restrict__ rowlist, float* __restrict__ gatelist) {
    const int wid  = threadIdx.x >> 6;
    const int lane = threadIdx.x & 63;
    const int t = blockIdx.x * 4 + wid;
    float acc[NE];
#pragma unroll
    for (int e = 0; e < NE; ++e) acc[e] = 0.f;
    const float* xr = x + (size_t)t * DIM;
    for (int d = lane; d < DIM; d += 64) {
        const float xv = xr[d];
        const float* wr = Wg + (size_t)d * NE;
#pragma unroll
        for (int e = 0; e < NE; ++e) acc[e] += xv * wr[e];
    }
#pragma unroll
    for (int off = 32; off > 0; off >>= 1) {
#pragma unroll
        for (int e = 0; e < NE; ++e) acc[e] += __shfl_xor(acc[e], off);
    }
    if (lane == 0) {
        float lg[NE];
#pragma unroll
        for (int e = 0; e < NE; ++e) lg[e] = acc[e] + bg[e];
        int i1 = 0; float v1 = lg[0];
#pragma unroll
        for (int e = 1; e < NE; ++e) if (lg[e] > v1) { v1 = lg[e]; i1 = e; }
        int i2 = -1; float v2 = -3.4e38f;
#pragma unroll
        for (int e = 0; e < NE; ++e) if (e != i1 && lg[e] > v2) { v2 = lg[e]; i2 = e; }
        const float ex = expf(v2 - v1);            // v1 >= v2
        const float g1 = 1.f / (1.f + ex);
        const float g2 = ex / (1.f + ex);
        int p1 = atomicAdd(&counts[i1], 1);
        rowlist[i1 * T_TOKENS + p1] = t * 2;
        gatelist[i1 * T_TOKENS + p1] = g1;
        int p2 = atomicAdd(&counts[i2], 1);
        rowlist[i2 * T_TOKENS + p2] = t * 2 + 1;
        gatelist[i2 * T_TOKENS + p2] = g2;
    }
}

// ---------------- x -> bf16 ----------------
__global__ void conv_bf16_kernel(const float* __restrict__ x, unsigned short* __restrict__ xb) {
    const int i = blockIdx.x * 256 + threadIdx.x;
    const float4 v = ((const float4*)x)[i];
    ushort4 o;
    o.x = f2bf(v.x); o.y = f2bf(v.y); o.z = f2bf(v.z); o.w = f2bf(v.w);
    ((ushort4*)xb)[i] = o;
}

// ---------------- out = x (residual base) ----------------
__global__ void init_out_kernel(const float* __restrict__ x, float* __restrict__ out) {
    const int i = blockIdx.x * 256 + threadIdx.x;
    ((float4*)out)[i] = ((const float4*)x)[i];
}

// ---------------- grouped GEMM, 64x64 tile, bf16 MFMA 16x16x32 ----------------
// PHASE 1: h[rid] = gelu(x[rid>>1] @ W1[e] + b1[e])
// PHASE 2: out[rid>>1] += gate * (h[rid] @ W2[e] + b2[e])   (atomic)
template <int PHASE>
__global__ __launch_bounds__(256) void moe_gemm(
    const unsigned short* __restrict__ A, const float* __restrict__ W,
    const float* __restrict__ bias, const int* __restrict__ counts,
    const int* __restrict__ rowlist, const float* __restrict__ gatelist,
    unsigned short* __restrict__ h, float* __restrict__ out) {
    constexpr int K = (PHASE == 1) ? DIM : HID;
    constexpr int N = (PHASE == 1) ? HID : DIM;
    const int e = blockIdx.z;
    const int cnt = counts[e];
    const int rt = blockIdx.y;
    if (rt * 64 >= cnt) return;
    const int n0 = blockIdx.x * 64;

    __shared__ __align__(16) unsigned short As[64][40];     // [row][k+pad]
    __shared__ __align__(16) unsigned short Bs[4][64][8];   // [k/8][n][k%8]
    __shared__ int rows_s[64];
    __shared__ float gates_s[64];

    const int tid = threadIdx.x;
    if (tid < 64) {
        const int gr = rt * 64 + tid;
        const int src = e * T_TOKENS + ((gr < cnt) ? gr : 0);
        rows_s[tid] = rowlist[src];
        gates_s[tid] = (gr < cnt) ? gatelist[src] : 0.f;
    }
    __syncthreads();

    // A staging map: thread -> (row, 8 consecutive k)
    const int arow = tid >> 2;
    const int acol = (tid & 3) * 8;
    const int rid = rows_s[arow];
    const unsigned short* aptr =
        A + (size_t)((PHASE == 1) ? (rid >> 1) : rid) * K + acol;

    // B staging map: thread -> (col n, 8 k rows), loads coalesced across lanes
    const int bn = tid & 63;
    const int bkb = tid >> 6;
    const float* wptr = W + (size_t)e * K * N + (size_t)bkb * 8 * N + n0 + bn;

    const int lane = tid & 63;
    const int wr = (tid >> 6) >> 1;   // wave row (2x2 waves, 32x32 each)
    const int wc = (tid >> 6) & 1;

    f32x4 acc[2][2];
#pragma unroll
    for (int m = 0; m < 2; ++m)
#pragma unroll
        for (int n = 0; n < 2; ++n)
#pragma unroll
            for (int r = 0; r < 4; ++r) acc[m][n][r] = 0.f;

    for (int k0 = 0; k0 < K; k0 += 32) {
        const uint4 av = *(const uint4*)(aptr + k0);
        float bv[8];
#pragma unroll
        for (int j = 0; j < 8; ++j) bv[j] = wptr[(size_t)(k0 + j) * N];
        __syncthreads();   // previous iteration's LDS reads complete
        *(uint4*)(&As[arow][acol]) = av;
        uint4 pk;
        pk.x = (unsigned)f2bf(bv[0]) | ((unsigned)f2bf(bv[1]) << 16);
        pk.y = (unsigned)f2bf(bv[2]) | ((unsigned)f2bf(bv[3]) << 16);
        pk.z = (unsigned)f2bf(bv[4]) | ((unsigned)f2bf(bv[5]) << 16);
        pk.w = (unsigned)f2bf(bv[6]) | ((unsigned)f2bf(bv[7]) << 16);
        *(uint4*)(&Bs[bkb][bn][0]) = pk;
        __syncthreads();

        short8 af[2], bfg[2];
#pragma unroll
        for (int m = 0; m < 2; ++m)
            af[m] = *(const short8*)(&As[wr * 32 + m * 16 + (lane & 15)][(lane >> 4) * 8]);
#pragma unroll
        for (int n = 0; n < 2; ++n)
            bfg[n] = *(const short8*)(&Bs[lane >> 4][wc * 32 + n * 16 + (lane & 15)][0]);
#pragma unroll
        for (int m = 0; m < 2; ++m)
#pragma unroll
            for (int n = 0; n < 2; ++n)
                acc[m][n] = __builtin_amdgcn_mfma_f32_16x16x32_bf16(af[m], bfg[n], acc[m][n], 0, 0, 0);
    }

    // epilogue: C/D layout col=lane&15, row=(lane>>4)*4+r  [guide §3, m89-verified]
#pragma unroll
    for (int m = 0; m < 2; ++m)
#pragma unroll
        for (int n = 0; n < 2; ++n) {
            const int col = n0 + wc * 32 + n * 16 + (lane & 15);
#pragma unroll
            for (int r = 0; r < 4; ++r) {
                const int rl = wr * 32 + m * 16 + (lane >> 4) * 4 + r;
                if (rt * 64 + rl < cnt) {
                    if (PHASE == 1) {
                        const float v = acc[m][n][r] + bias[(size_t)e * N + col];
                        // tanh-approx gelu == v * sigmoid(1.5957691f*(v + 0.044715 v^3))
                        const float s = 1.f / (1.f + __expf(-1.5957691216f * (v + 0.044715f * v * v * v)));
                        h[(size_t)rows_s[rl] * HID + col] = f2bf(v * s);
                    } else {
                        const float v = (acc[m][n][r] + bias[(size_t)e * N + col]) * gates_s[rl];
                        atomicAdd(&out[(size_t)(rows_s[rl] >> 1) * DIM + col], v);
                    }
                }
            }
        }
}

extern "C" void kernel_launch(void* const* d_in, const int* in_sizes, int n_in,
                              void* d_out, int out_size, void* d_ws, size_t ws_size,
                              hipStream_t stream) {
    (void)in_sizes; (void)n_in; (void)out_size; (void)ws_size;
    const float* x  = (const float*)d_in[0];
    const float* Wg = (const float*)d_in[1];
    const float* bg = (const float*)d_in[2];
    const float* W1 = (const float*)d_in[3];
    const float* b1 = (const float*)d_in[4];
    const float* W2 = (const float*)d_in[5];
    const float* b2 = (const float*)d_in[6];
    float* out = (float*)d_out;

    char* ws = (char*)d_ws;
    size_t off = 0;
    auto alloc = [&](size_t bytes) -> void* {
        size_t a = (off + 255) & ~(size_t)255;
        off = a + bytes;
        return (void*)(ws + a);
    };
    int*   counts   = (int*)alloc(NE * sizeof(int));
    int*   rowlist  = (int*)alloc((size_t)NE * T_TOKENS * sizeof(int));
    float* gatelist = (float*)alloc((size_t)NE * T_TOKENS * sizeof(float));
    unsigned short* xb = (unsigned short*)alloc((size_t)T_TOKENS * DIM * 2);
    unsigned short* h  = (unsigned short*)alloc((size_t)T_TOKENS * TOPK * HID * 2);
    // total ws use: ~72.6 MB

    hipMemsetAsync(counts, 0, NE * sizeof(int), stream);
    router_kernel<<<T_TOKENS / 4, 256, 0, stream>>>(x, Wg, bg, counts, rowlist, gatelist);
    const int nvec = T_TOKENS * DIM / 4;
    conv_bf16_kernel<<<nvec / 256, 256, 0, stream>>>(x, xb);
    init_out_kernel<<<nvec / 256, 256, 0, stream>>>(x, out);
    moe_gemm<1><<<dim3(HID / 64, T_TOKENS / 64, NE), 256, 0, stream>>>(
        xb, W1, b1, counts, rowlist, gatelist, h, nullptr);
    moe_gemm<2><<<dim3(DIM / 64, T_TOKENS / 64, NE), 256, 0, stream>>>(
        h, W2, b2, counts, rowlist, gatelist, nullptr, out);
}

// Round 2
// 506.059 us; speedup vs baseline: 1.1936x; 1.1936x over previous
//
#include <hip/hip_runtime.h>

#define T_TOKENS 4096
#define DIM      1024
#define HID      4096
#define NE       8
#define TOPK     2

typedef __attribute__((ext_vector_type(8))) short short8;
typedef __attribute__((ext_vector_type(4))) float f32x4;

__device__ __forceinline__ unsigned short f2bf(float f) {
    unsigned int u = __builtin_bit_cast(unsigned int, f);
    u += 0x7fffu + ((u >> 16) & 1u);
    return (unsigned short)(u >> 16);
}

__device__ __forceinline__ void gload16(const void* g, void* l) {
    __builtin_amdgcn_global_load_lds(
        (const __attribute__((address_space(1))) unsigned int*)g,
        (__attribute__((address_space(3))) unsigned int*)l, 16, 0, 0);
}

// ---------------- router: logits -> top2 -> softmax -> scatter ----------------
__global__ void router_kernel(const float* __restrict__ x, const float* __restrict__ Wg,
                              const float* __restrict__ bg, int* __restrict__ counts,
                              int* __restrict__ rowlist, float* __restrict__ gatelist) {
    const int wid  = threadIdx.x >> 6;
    const int lane = threadIdx.x & 63;
    const int t = blockIdx.x * 4 + wid;
    float acc[NE];
#pragma unroll
    for (int e = 0; e < NE; ++e) acc[e] = 0.f;
    const float* xr = x + (size_t)t * DIM;
    for (int d = lane; d < DIM; d += 64) {
        const float xv = xr[d];
        const float* wr = Wg + (size_t)d * NE;
#pragma unroll
        for (int e = 0; e < NE; ++e) acc[e] += xv * wr[e];
    }
#pragma unroll
    for (int off = 32; off > 0; off >>= 1) {
#pragma unroll
        for (int e = 0; e < NE; ++e) acc[e] += __shfl_xor(acc[e], off);
    }
    if (lane == 0) {
        float lg[NE];
#pragma unroll
        for (int e = 0; e < NE; ++e) lg[e] = acc[e] + bg[e];
        int i1 = 0; float v1 = lg[0];
#pragma unroll
        for (int e = 1; e < NE; ++e) if (lg[e] > v1) { v1 = lg[e]; i1 = e; }
        int i2 = -1; float v2 = -3.4e38f;
#pragma unroll
        for (int e = 0; e < NE; ++e) if (e != i1 && lg[e] > v2) { v2 = lg[e]; i2 = e; }
        const float ex = expf(v2 - v1);            // v1 >= v2
        const float g1 = 1.f / (1.f + ex);
        const float g2 = ex / (1.f + ex);
        int p1 = atomicAdd(&counts[i1], 1);
        rowlist[i1 * T_TOKENS + p1] = t * 2;
        gatelist[i1 * T_TOKENS + p1] = g1;
        int p2 = atomicAdd(&counts[i2], 1);
        rowlist[i2 * T_TOKENS + p2] = t * 2 + 1;
        gatelist[i2 * T_TOKENS + p2] = g2;
    }
}

// ---------------- x -> bf16 ----------------
__global__ void conv_bf16_kernel(const float* __restrict__ x, unsigned short* __restrict__ xb) {
    const int i = blockIdx.x * 256 + threadIdx.x;
    const float4 v = ((const float4*)x)[i];
    ushort4 o;
    o.x = f2bf(v.x); o.y = f2bf(v.y); o.z = f2bf(v.z); o.w = f2bf(v.w);
    ((ushort4*)xb)[i] = o;
}

// ---------------- out = x (residual base) ----------------
__global__ void init_out_kernel(const float* __restrict__ x, float* __restrict__ out) {
    const int i = blockIdx.x * 256 + threadIdx.x;
    ((float4*)out)[i] = ((const float4*)x)[i];
}

// ---------------- W [e][K][N] f32 -> Wb [e][N][K] bf16 (transpose-convert) ---
template <int K, int N>
__global__ __launch_bounds__(256) void transconv_kernel(const float* __restrict__ W,
                                                        unsigned short* __restrict__ Wb) {
    const int e  = blockIdx.z;
    const int k0 = blockIdx.y * 64;
    const int nb = blockIdx.x * 64;
    __shared__ unsigned short t[64][72];
    const int tid = threadIdx.x;
    const int r  = tid >> 4;
    const int c4 = (tid & 15) * 4;
    const float* src = W + (size_t)e * K * N + (size_t)(k0 + r) * N + nb + c4;
#pragma unroll
    for (int p = 0; p < 4; ++p) {
        const float4 v = *(const float4*)(src + (size_t)p * 16 * N);
        ushort4 o;
        o.x = f2bf(v.x); o.y = f2bf(v.y); o.z = f2bf(v.z); o.w = f2bf(v.w);
        *(ushort4*)(&t[r + p * 16][c4]) = o;
    }
    __syncthreads();
#pragma unroll
    for (int p = 0; p < 4; ++p) {
        const int n  = (tid >> 4) + p * 16;
        const int kk = (tid & 15) * 4;
        ushort4 o;
        o.x = t[kk][n]; o.y = t[kk + 1][n]; o.z = t[kk + 2][n]; o.w = t[kk + 3][n];
        *(ushort4*)(Wb + (size_t)e * N * K + (size_t)(nb + n) * K + k0 + kk) = o;
    }
}

// ---------------- grouped GEMM, 128x128 tile, m97 structure ----------------
// PHASE 1: h[rid] = gelu(x[rid>>1] @ W1[e] + b1[e])
// PHASE 2: out[rid>>1] += gate * (h[rid] @ W2[e] + b2[e])   (atomic)
// Wb layout: [e][n][k] bf16 (pre-transposed), A layout: [row][k] bf16.
template <int PHASE>
__global__ __launch_bounds__(256) void moe_gemm(
    const unsigned short* __restrict__ A, const unsigned short* __restrict__ Wb,
    const float* __restrict__ bias, const int* __restrict__ counts,
    const int* __restrict__ rowlist, const float* __restrict__ gatelist,
    unsigned short* __restrict__ h, float* __restrict__ out) {
    constexpr int K = (PHASE == 1) ? DIM : HID;
    constexpr int N = (PHASE == 1) ? HID : DIM;
    const int e = blockIdx.z;
    const int cnt = counts[e];
    const int rt = blockIdx.y;
    if (rt * 128 >= cnt) return;
    const int n0 = blockIdx.x * 128;

    __shared__ __align__(16) unsigned short As[128][32];
    __shared__ __align__(16) unsigned short Bs[128][32];
    __shared__ int rows_s[128];
    __shared__ float gates_s[128];

    const int tid = threadIdx.x;
    if (tid < 128) {
        const int gr = rt * 128 + tid;
        const int src = e * T_TOKENS + ((gr < cnt) ? gr : 0);
        rows_s[tid] = rowlist[src];
        gates_s[tid] = (gr < cnt) ? gatelist[src] : 0.f;
    }
    __syncthreads();

    const int lane = tid & 63;
    const int wid = tid >> 6;

    // staging map: wave wid, instr j covers 16 consecutive tile-rows starting
    // r0=(wid*2+j)*16; lane l -> row r0+(l>>2), k-offset (l&3)*8. LDS dest is
    // wave-uniform base + lane*16 (global_load_lds semantics); source per-lane.
    const unsigned short* srcA[2];
    const unsigned short* srcB[2];
    unsigned short* ldsA[2];
    unsigned short* ldsB[2];
#pragma unroll
    for (int j = 0; j < 2; ++j) {
        const int r0 = (wid * 2 + j) * 16;
        const int r = r0 + (lane >> 2);
        const int kofs = (lane & 3) * 8;
        const int rid = rows_s[r];
        srcA[j] = A + (size_t)((PHASE == 1) ? (rid >> 1) : rid) * K + kofs;
        srcB[j] = Wb + (size_t)e * N * K + (size_t)(n0 + r) * K + kofs;
        ldsA[j] = &As[0][0] + r0 * 32;
        ldsB[j] = &Bs[0][0] + r0 * 32;
    }

    const int wr = wid >> 1;   // 2x2 waves, each owns 64x64
    const int wc = wid & 1;

    f32x4 acc[4][4];
#pragma unroll
    for (int m = 0; m < 4; ++m)
#pragma unroll
        for (int n = 0; n < 4; ++n)
#pragma unroll
            for (int r = 0; r < 4; ++r) acc[m][n][r] = 0.f;

    for (int k0 = 0; k0 < K; k0 += 32) {
#pragma unroll
        for (int j = 0; j < 2; ++j) {
            gload16(srcA[j] + k0, ldsA[j]);
            gload16(srcB[j] + k0, ldsB[j]);
        }
        __syncthreads();   // drains vmcnt(0) -> staged data visible

        short8 af[4], bfr[4];
#pragma unroll
        for (int m = 0; m < 4; ++m)
            af[m] = *(const short8*)(&As[wr * 64 + m * 16 + (lane & 15)][(lane >> 4) * 8]);
#pragma unroll
        for (int n = 0; n < 4; ++n)
            bfr[n] = *(const short8*)(&Bs[wc * 64 + n * 16 + (lane & 15)][(lane >> 4) * 8]);
#pragma unroll
        for (int m = 0; m < 4; ++m)
#pragma unroll
            for (int n = 0; n < 4; ++n)
                acc[m][n] = __builtin_amdgcn_mfma_f32_16x16x32_bf16(af[m], bfr[n], acc[m][n], 0, 0, 0);
        __syncthreads();   // compute done before next-iter staging overwrites
    }

    // epilogue: C/D layout col=lane&15, row=(lane>>4)*4+r
#pragma unroll
    for (int n = 0; n < 4; ++n) {
        const int col = n0 + wc * 64 + n * 16 + (lane & 15);
        const float bv = bias[(size_t)e * N + col];
#pragma unroll
        for (int m = 0; m < 4; ++m) {
            const int rbase = wr * 64 + m * 16 + (lane >> 4) * 4;
#pragma unroll
            for (int r = 0; r < 4; ++r) {
                const int row = rbase + r;
                if (rt * 128 + row < cnt) {
                    if (PHASE == 1) {
                        const float v = acc[m][n][r] + bv;
                        // tanh-approx gelu == v * sigmoid(1.5957691*(v+0.044715 v^3))
                        const float s = 1.f / (1.f + __expf(-1.5957691216f * (v + 0.044715f * v * v * v)));
                        h[(size_t)rows_s[row] * HID + col] = f2bf(v * s);
                    } else {
                        const float v = (acc[m][n][r] + bv) * gates_s[row];
                        atomicAdd(&out[(size_t)(rows_s[row] >> 1) * DIM + col], v);
                    }
                }
            }
        }
    }
}

extern "C" void kernel_launch(void* const* d_in, const int* in_sizes, int n_in,
                              void* d_out, int out_size, void* d_ws, size_t ws_size,
                              hipStream_t stream) {
    (void)in_sizes; (void)n_in; (void)out_size; (void)ws_size;
    const float* x  = (const float*)d_in[0];
    const float* Wg = (const float*)d_in[1];
    const float* bg = (const float*)d_in[2];
    const float* W1 = (const float*)d_in[3];
    const float* b1 = (const float*)d_in[4];
    const float* W2 = (const float*)d_in[5];
    const float* b2 = (const float*)d_in[6];
    float* out = (float*)d_out;

    char* ws = (char*)d_ws;
    size_t off = 0;
    auto alloc = [&](size_t bytes) -> void* {
        size_t a = (off + 255) & ~(size_t)255;
        off = a + bytes;
        return (void*)(ws + a);
    };
    int*   counts   = (int*)alloc(NE * sizeof(int));
    int*   rowlist  = (int*)alloc((size_t)NE * T_TOKENS * sizeof(int));
    float* gatelist = (float*)alloc((size_t)NE * T_TOKENS * sizeof(float));
    unsigned short* xb  = (unsigned short*)alloc((size_t)T_TOKENS * DIM * 2);
    unsigned short* h   = (unsigned short*)alloc((size_t)T_TOKENS * TOPK * HID * 2);
    unsigned short* W1b = (unsigned short*)alloc((size_t)NE * DIM * HID * 2);
    unsigned short* W2b = (unsigned short*)alloc((size_t)NE * HID * DIM * 2);
    // total ws use: ~200.3 MB

    hipMemsetAsync(counts, 0, NE * sizeof(int), stream);
    router_kernel<<<T_TOKENS / 4, 256, 0, stream>>>(x, Wg, bg, counts, rowlist, gatelist);
    const int nvec = T_TOKENS * DIM / 4;
    conv_bf16_kernel<<<nvec / 256, 256, 0, stream>>>(x, xb);
    init_out_kernel<<<nvec / 256, 256, 0, stream>>>(x, out);
    transconv_kernel<DIM, HID><<<dim3(HID / 64, DIM / 64, NE), 256, 0, stream>>>(W1, W1b);
    transconv_kernel<HID, DIM><<<dim3(DIM / 64, HID / 64, NE), 256, 0, stream>>>(W2, W2b);
    moe_gemm<1><<<dim3(HID / 128, T_TOKENS / 128, NE), 256, 0, stream>>>(
        xb, W1b, b1, counts, rowlist, gatelist, h, nullptr);
    moe_gemm<2><<<dim3(DIM / 128, T_TOKENS / 128, NE), 256, 0, stream>>>(
        h, W2b, b2, counts, rowlist, gatelist, nullptr, out);
}